// Round 5
// baseline (230.177 us; speedup 1.0000x reference)
//
#include <hip/hip_runtime.h>
#include <math.h>

#define H 512
#define W 512
#define IMG (H*W)
#define NIMG 32           // 16 images from y_hat + 16 from y
#define NSTRIP 10         // 56-col output strips per row
#define SW 56
#define RB 32             // output rows per band (one cohort: 5120 waves, 5 blk/CU)
#define NBAND 16          // 16*32 = 512 exactly

typedef unsigned long long u64;

__device__ __forceinline__ int reflect_idx(int i, int n) {
    if (i < 0) i = -i;
    if (i >= n) i = 2 * n - 2 - i;
    return i;
}

// All cross-lane via ds_bpermute (r0/r4-proven): no VALU->DPP hazard nops;
// DS latency cross-hides across the 5 resident waves/SIMD, and in-order DS
// return lets counted lgkmcnt waits overlap next-pair shuffles (see STEP).
__device__ __forceinline__ float bperm_f(int addr, float v) {
    return __int_as_float(__builtin_amdgcn_ds_bpermute(addr, __float_as_int(v)));
}

// Composed 7-tap kernels: blur(5-tap gaussian) composed with sobel [1,2,1]/[-1,0,1].
#define S0c 0.05448868454964294f
#define S1c 0.35317871110251920f
#define S2c 0.94551131545035710f
#define S3c 1.29364257779496160f
#define A1c 0.05448868454964294f
#define A2c 0.24420134200323332f
#define A3c 0.34813126234460456f

// ---------------------------------------------------------------------------
// Kernel 1 (line-scan, row-PAIR + one-pair shuffle pipeline, depth-2 loads):
// one wave per (image,strip,band). Lane = gray col 56s-4+lane.
//  - Ping-pong load sets A/B, loads issued 2-3 pair-bodies before use.
//  - Ring h-FIFO depth 8, literal indices (zero FIFO movs).
//  - Pair k+1's 12 bpermutes are issued BEFORE pair k's NMS tail, so the
//    NMS waits with lgkmcnt(12) while next-pair shuffles stay in flight.
// Output: 56-bit words, plane[img][strip][row].
// ---------------------------------------------------------------------------
__global__ __launch_bounds__(256, 5) void k_edges(const float* __restrict__ yhat,
                                                  const float* __restrict__ yy,
                                                  u64* __restrict__ strongP,
                                                  u64* __restrict__ weakP) {
    const int wid = blockIdx.x * 4 + (threadIdx.x >> 6);
    const int lane = threadIdx.x & 63;

    const int n = wid / (NSTRIP * NBAND);
    const int rem = wid - n * (NSTRIP * NBAND);
    const int s = rem / NBAND;
    const int band = rem - s * NBAND;
    const int y0 = band * RB;
    const float* src = (n < 16) ? (yhat + (size_t)n * 3 * IMG)
                                : (yy + (size_t)(n - 16) * 3 * IMG);
    const float* __restrict__ srcR = src;
    const float* __restrict__ srcG = src + IMG;
    const float* __restrict__ srcB = src + 2 * IMG;

    const int c = s * SW - 4 + lane;
    const int cx = reflect_idx(c, W);
    const bool colok = ((unsigned)c < (unsigned)W);
    const u64 omask = (s == 9) ? 0xFFull : 0x00FFFFFFFFFFFFFFull;

    const int aM1 = ((lane - 1) << 2), aP1 = ((lane + 1) << 2);
    const int aM2 = ((lane - 2) << 2), aP2 = ((lane + 2) << 2);
    const int aM3 = ((lane - 3) << 2), aP3 = ((lane + 3) << 2);

    float hx[8], hy[8];
#pragma unroll
    for (int j = 0; j < 8; j++) { hx[j] = 0.f; hy[j] = 0.f; }

    const u64 outBase = ((size_t)n * NSTRIP + s) * H;

    // ping-pong prefetch register sets: A = even pairs, B = odd pairs
    float rA0, gA0, bA0, rA1, gA1, bA1;
    float rB0, gB0, bB0, rB1, gB1, bB1;

    // persistent shuffle temps (pipeline registers) + current-pair grays
    float sam1, sap1, sam2, sap2, sam3, sap3;
    float sbm1, sbp1, sbm2, sbp2, sbm3, sbp3;
    float gcur0, gcur1;

    // load gray-source rows y0-4+2kk, y0-3+2kk into set S
#define LOADP(S, kk)                                                            \
    {                                                                           \
        int ya = y0 - 4 + 2 * (kk), yb = ya + 1;                                \
        int ia = reflect_idx(ya, H), ib = reflect_idx(yb, H);                   \
        int voa = (ia << 9) + cx, vob = (ib << 9) + cx;                         \
        r##S##0 = srcR[voa]; g##S##0 = srcG[voa]; b##S##0 = srcB[voa];          \
        r##S##1 = srcR[vob]; g##S##1 = srcG[vob]; b##S##1 = srcB[vob];          \
    }

    // issue 6 bpermutes for one gray row into persistent temps t*
#define SHUF6(gv, t)                                                            \
    t##m1 = bperm_f(aM1, gv); t##p1 = bperm_f(aP1, gv);                         \
    t##m2 = bperm_f(aM2, gv); t##p2 = bperm_f(aP2, gv);                         \
    t##m3 = bperm_f(aM3, gv); t##p3 = bperm_f(aP3, gv);

    // combine shuffles into ring slot P (compile-time literal)
#define COMB(gv, t, P)                                                          \
    hx[(P) & 7] = A3c * (t##p1 - t##m1) + A2c * (t##p2 - t##m2)                 \
                + A1c * (t##p3 - t##m3);                                        \
    hy[(P) & 7] = S3c * (gv) + S2c * (t##p1 + t##m1) + S1c * (t##p2 + t##m2)    \
                + S0c * (t##p3 + t##m3);

    // mag^2 + L/R + dir for ring center CP (literal); row mr gates validity
#define MAG_AT(CP, mr, mv, mvL, mvR, dv)                                        \
    {                                                                           \
        float gx = S3c * hx[(CP) & 7]                                           \
                 + S2c * (hx[((CP) + 1) & 7] + hx[((CP) + 7) & 7])              \
                 + S1c * (hx[((CP) + 2) & 7] + hx[((CP) + 6) & 7])              \
                 + S0c * (hx[((CP) + 3) & 7] + hx[((CP) + 5) & 7]);             \
        float gy = A3c * (hy[((CP) + 1) & 7] - hy[((CP) + 7) & 7])              \
                 + A2c * (hy[((CP) + 2) & 7] - hy[((CP) + 6) & 7])              \
                 + A1c * (hy[((CP) + 3) & 7] - hy[((CP) + 5) & 7]);             \
        bool okm = colok && ((unsigned)(mr) < (unsigned)H);                     \
        mv = okm ? (gx * gx + gy * gy + 1e-12f) : 0.f;                          \
        mvL = bperm_f(aM1, mv);                                                 \
        mvR = bperm_f(aP1, mv);                                                 \
        float ax = fabsf(gx), ay = fabsf(gy);                                   \
        dv = (ay <= 0.4142135623730951f * ax) ? 0                               \
           : (ay >= 2.414213562373095f * ax) ? 2                                \
           : (((gx > 0.f) == (gy > 0.f)) ? 1 : 3);                              \
    }

#define GRAY0(S) (0.299f * r##S##0 + 0.587f * g##S##0 + 0.114f * b##S##0)
#define GRAY1(S) (0.299f * r##S##1 + 0.587f * g##S##1 + 0.114f * b##S##1)

    LOADP(A, 0);
    LOADP(B, 1);

    // ---- prime pairs 0..2: fill ring slots 0..5 (gray rows y0-4..y0+1) ----
#define PRIME(kk, S)                                                            \
    {                                                                           \
        float ga = GRAY0(S);                                                    \
        float gb = GRAY1(S);                                                    \
        LOADP(S, (kk) + 2);                                                     \
        SHUF6(ga, sa)                                                           \
        SHUF6(gb, sb)                                                           \
        COMB(ga, sa, 2 * (kk))                                                  \
        COMB(gb, sb, 2 * (kk) + 1)                                              \
    }
    PRIME(0, A)
    PRIME(1, B)
    PRIME(2, A)
#undef PRIME

    // pair 3 (B): gray rows y0+2,y0+3 -> mag rows y0-1, y0; then pre-issue
    // pair 4's grays + shuffles (pipeline prologue).
    float mm1, mm1L, mm1R, m0, m0L, m0R;
    int dir0;
    {
        float ga = GRAY0(B);
        float gb = GRAY1(B);
        LOADP(B, 5);
        SHUF6(ga, sa)
        SHUF6(gb, sb)
        COMB(ga, sa, 6)
        int dtmp;
        MAG_AT(3, y0 - 1, mm1, mm1L, mm1R, dtmp);
        (void)dtmp;
        COMB(gb, sb, 7)
        MAG_AT(4, y0, m0, m0L, m0R, dir0);
        // prepare pair 4 (set A)
        gcur0 = GRAY0(A);
        gcur1 = GRAY1(A);
        LOADP(A, 6);
        SHUF6(gcur0, sa)
        SHUF6(gcur1, sb)
    }

    // ---- steady step: jj = k&3 (literal ring phase), SN = set of pair k+1.
    // Consumes in-flight shuffles (sa/sb, gcur*) for pair k; issues pair
    // k+1's shuffles before the NMS tail; loads pair k+3 into SN. ----
#define STEP(jj, k, SN, DOPREF, DONEXT)                                         \
    {                                                                           \
        float ma, maL, maR, mb, mbL, mbR;                                       \
        int da, db;                                                             \
        COMB(gcur0, sa, 2 * (jj))                                               \
        MAG_AT((2 * (jj) + 5) & 7, y0 + 2 * (k) - 7, ma, maL, maR, da);         \
        COMB(gcur1, sb, 2 * (jj) + 1)                                           \
        MAG_AT((2 * (jj) + 6) & 7, y0 + 2 * (k) - 6, mb, mbL, mbR, db);         \
        if (DONEXT) {                                                           \
            gcur0 = GRAY0(SN);                                                  \
            gcur1 = GRAY1(SN);                                                  \
            if (DOPREF) LOADP(SN, (k) + 3);                                     \
            SHUF6(gcur0, sa)                                                    \
            SHUF6(gcur1, sb)                                                    \
        }                                                                       \
        /* row t0 = y0+2k-8: mags (mm1, m0, ma), dir0 */                        \
        float n1 = (dir0 == 0) ? m0R : (dir0 == 1) ? maR : (dir0 == 2) ? ma : maL; \
        float n2 = (dir0 == 0) ? m0L : (dir0 == 1) ? mm1L : (dir0 == 2) ? mm1 : mm1R; \
        bool ok0 = (m0 >= n1) && (m0 >= n2);                                    \
        u64 bs0 = __ballot(ok0 && (m0 >= 0.04f));                               \
        u64 bw0 = __ballot(ok0 && (m0 >= 0.01f));                               \
        /* row t1 = t0+1: mags (m0, ma, mb), dir = da */                        \
        float n3 = (da == 0) ? maR : (da == 1) ? mbR : (da == 2) ? mb : mbL;    \
        float n4 = (da == 0) ? maL : (da == 1) ? m0L : (da == 2) ? m0 : m0R;    \
        bool ok1 = (ma >= n3) && (ma >= n4);                                    \
        u64 bs1 = __ballot(ok1 && (ma >= 0.04f));                               \
        u64 bw1 = __ballot(ok1 && (ma >= 0.01f));                               \
        if (lane == 0) {                                                        \
            int t0 = y0 + 2 * (k) - 8;                                          \
            ulonglong2 vs, vw;                                                  \
            vs.x = (bs0 >> 4) & omask; vs.y = (bs1 >> 4) & omask;               \
            vw.x = (bw0 >> 4) & omask; vw.y = (bw1 >> 4) & omask;               \
            *(ulonglong2*)&strongP[outBase + t0] = vs;                          \
            *(ulonglong2*)&weakP[outBase + t0] = vw;                            \
        }                                                                       \
        mm1 = ma; mm1L = maL; mm1R = maR;                                       \
        m0 = mb; m0L = mbL; m0R = mbR;                                          \
        dir0 = db;                                                              \
    }

    // steady pairs k=4..19; pair parity: even->A, odd->B (SN = next pair's set)
#pragma unroll 1
    for (int k4 = 4; k4 < 16; k4 += 4) {
        STEP(0, k4 + 0, B, true, true);
        STEP(1, k4 + 1, A, true, true);
        STEP(2, k4 + 2, B, true, true);
        STEP(3, k4 + 3, A, true, true);
    }
    STEP(0, 16, B, true, true);     // loads (B,19) — last prefetch
    STEP(1, 17, A, false, true);
    STEP(2, 18, B, false, true);
    STEP(3, 19, A, false, false);   // last pair: nothing to pre-issue

#undef STEP
#undef MAG_AT
#undef COMB
#undef SHUF6
#undef LOADP
#undef GRAY0
#undef GRAY1
}

// ---------------------------------------------------------------------------
// Kernel 2: bit-parallel hysteresis (10 iters, exact via light cone) + diff
// count -> per-block partial. NO device fence / atomics: the fused-finalize
// variant's per-block __threadfence() cost ~20-25 µs total on gfx950 (L2
// writeback across non-coherent XCDs, x1024 blocks). Kernel-boundary
// ordering + separate k_final is ~2 µs.
// One wave per 32x32 tile per image-pair; lane l = row ty0-10+l.
// Loads from 56-bit strip words via 3-word funnel shift (coalesced: lane=y).
// ---------------------------------------------------------------------------
__device__ __forceinline__ u64 ldw10(const u64* p, int img, int y, int q, bool ok) {
    return (ok && q >= 0 && q < NSTRIP) ? p[((size_t)img * NSTRIP + q) * H + y] : 0ULL;
}

__global__ __launch_bounds__(256) void k_hyst(const u64* __restrict__ strongP,
                                              const u64* __restrict__ weakP,
                                              unsigned int* __restrict__ partials) {
    __shared__ unsigned int part[4];
    const int wy = threadIdx.x >> 6;
    const int wave = blockIdx.x * 4 + wy;
    const int lane = threadIdx.x & 63;
    const int tile = wave & 255;
    const int pair = wave >> 8;          // 0..15
    const int tx0 = (tile & 15) * 32;
    const int ty0 = (tile >> 4) * 32;

    const int y = ty0 - 10 + lane;
    const bool rowok = (lane < 52) && (y >= 0) && (y < H);
    const int yc = rowok ? y : 0;

    const int x = tx0 - 10;
    const int q0 = (x < 0) ? -1 : (x / 56);
    const int r = x - 56 * q0;           // 1..55, never 0
    const int sh1 = 56 - r;
    const bool need3 = (r > 48);
    const int sh2 = 112 - r;

    const int imgA = pair, imgB = pair + 16;
    u64 sA, wA, sB, wB;
    {
        u64 w0, w1, w2;
        w0 = ldw10(strongP, imgA, yc, q0, rowok);
        w1 = ldw10(strongP, imgA, yc, q0 + 1, rowok);
        w2 = need3 ? ldw10(strongP, imgA, yc, q0 + 2, rowok) : 0ULL;
        sA = (w0 >> r) | (w1 << sh1) | (need3 ? (w2 << sh2) : 0ULL);
        w0 = ldw10(weakP, imgA, yc, q0, rowok);
        w1 = ldw10(weakP, imgA, yc, q0 + 1, rowok);
        w2 = need3 ? ldw10(weakP, imgA, yc, q0 + 2, rowok) : 0ULL;
        wA = (w0 >> r) | (w1 << sh1) | (need3 ? (w2 << sh2) : 0ULL);
        w0 = ldw10(strongP, imgB, yc, q0, rowok);
        w1 = ldw10(strongP, imgB, yc, q0 + 1, rowok);
        w2 = need3 ? ldw10(strongP, imgB, yc, q0 + 2, rowok) : 0ULL;
        sB = (w0 >> r) | (w1 << sh1) | (need3 ? (w2 << sh2) : 0ULL);
        w0 = ldw10(weakP, imgB, yc, q0, rowok);
        w1 = ldw10(weakP, imgB, yc, q0 + 1, rowok);
        w2 = need3 ? ldw10(weakP, imgB, yc, q0 + 2, rowok) : 0ULL;
        wB = (w0 >> r) | (w1 << sh1) | (need3 ? (w2 << sh2) : 0ULL);
    }

#pragma unroll
    for (int it = 0; it < 10; it++) {
        u64 up = __shfl_up(sA, 1), dn = __shfl_down(sA, 1);
        u64 t = up | sA | dn;
        sA |= (t | (t << 1) | (t >> 1)) & wA;
        up = __shfl_up(sB, 1); dn = __shfl_down(sB, 1);
        t = up | sB | dn;
        sB |= (t | (t << 1) | (t >> 1)) & wB;
    }

    unsigned int cgt = 0;
    if (lane >= 10 && lane < 42) {
        const u64 mask = ((1ULL << 42) - (1ULL << 10));
        cgt = (unsigned int)__popcll((sA ^ sB) & mask);
    }
#pragma unroll
    for (int off = 32; off > 0; off >>= 1) cgt += __shfl_down(cgt, off);
    if (lane == 0) part[wy] = cgt;
    __syncthreads();
    if (threadIdx.x == 0)
        partials[blockIdx.x] = part[0] + part[1] + part[2] + part[3];
}

// ---------------------------------------------------------------------------
// Kernel 3: sum 1024 partials, scale, write scalar. One block.
// ---------------------------------------------------------------------------
__global__ __launch_bounds__(256) void k_final(const unsigned int* __restrict__ partials,
                                               float* __restrict__ out) {
    __shared__ unsigned int part[4];
    unsigned int c = 0;
    for (int i = threadIdx.x; i < 1024; i += 256) c += partials[i];
#pragma unroll
    for (int off = 32; off > 0; off >>= 1) c += __shfl_down(c, off);
    const int lane = threadIdx.x & 63;
    const int wy = threadIdx.x >> 6;
    if (lane == 0) part[wy] = c;
    __syncthreads();
    if (threadIdx.x == 0)
        out[0] = (float)(part[0] + part[1] + part[2] + part[3]) * (1.0f / 4194304.0f);
}

extern "C" void kernel_launch(void* const* d_in, const int* in_sizes, int n_in,
                              void* d_out, int out_size, void* d_ws, size_t ws_size,
                              hipStream_t stream) {
    const float* yhat = (const float*)d_in[0];
    const float* yy = (const float*)d_in[1];

    u64* strongP = (u64*)d_ws;                        // 32*10*512 u64 = 1.31 MB
    u64* weakP = strongP + (size_t)NIMG * NSTRIP * H; // 1.31 MB
    unsigned int* partials = (unsigned int*)(weakP + (size_t)NIMG * NSTRIP * H);

    // 32 img x 10 strips x 16 bands = 5120 waves, 4 waves/block, 5 blk/CU
    k_edges<<<1280, 256, 0, stream>>>(yhat, yy, strongP, weakP);

    // 256 tiles x 16 pairs = 4096 waves, 4 waves/block
    k_hyst<<<1024, 256, 0, stream>>>(strongP, weakP, partials);
    k_final<<<1, 256, 0, stream>>>(partials, (float*)d_out);
}

// Round 6
// 136.145 us; speedup vs baseline: 1.6907x; 1.6907x over previous
//
#include <hip/hip_runtime.h>
#include <math.h>

#define H 512
#define W 512
#define IMG (H*W)
#define NIMG 32           // 16 images from y_hat + 16 from y
#define NSTRIP 10         // 56-col output strips per row
#define SW 56
#define RB 32             // output rows per band (one cohort: 5120 waves, 5 blk/CU)
#define NBAND 16          // 16*32 = 512 exactly

typedef unsigned long long u64;

__device__ __forceinline__ int reflect_idx(int i, int n) {
    if (i < 0) i = -i;
    if (i >= n) i = 2 * n - 2 - i;
    return i;
}

// All cross-lane via ds_bpermute (r0/r4-proven): no VALU->DPP hazard nops; DS
// latency cross-hides across the 5 resident waves/SIMD.
// NOTE (r5 lesson): do NOT software-pipeline the shuffles across pairs — the
// extra 12+ live temps push the allocator into occupancy-chasing spills
// (VGPR pinned 48 + 570 B/thread scratch -> 3.3x slowdown).
__device__ __forceinline__ float bperm_f(int addr, float v) {
    return __int_as_float(__builtin_amdgcn_ds_bpermute(addr, __float_as_int(v)));
}

// Composed 7-tap kernels: blur(5-tap gaussian) composed with sobel [1,2,1]/[-1,0,1].
#define S0c 0.05448868454964294f
#define S1c 0.35317871110251920f
#define S2c 0.94551131545035710f
#define S3c 1.29364257779496160f
#define A1c 0.05448868454964294f
#define A2c 0.24420134200323332f
#define A3c 0.34813126234460456f

// ---------------------------------------------------------------------------
// Kernel 1 (line-scan, row-PAIR pipelined, DEPTH-2 prefetch): one wave per
// (image,strip,band). Lane = gray col 56s-4+lane. Ping-pong register sets
// A/B hold pairs k (even->A, odd->B); pair k issues loads for pair k+2 into
// its own set -> load-to-use distance = 2 pair bodies. Ring h-FIFO depth 8,
// all indices compile-time literals (zero FIFO movs, zero scratch). Per pair:
// 12 bpermutes issued back-to-back (fine-grained lgkmcnt overlap), 2 combines,
// 2 MAG (+2 bperm each), 2 NMS rows, one 16B paired store.
// Measured (round-4 bench): 41.2-45.7 us, VGPR 44, no scratch.
// Output: 56-bit words, plane[img][strip][row].
// ---------------------------------------------------------------------------
__global__ __launch_bounds__(256, 5) void k_edges(const float* __restrict__ yhat,
                                                  const float* __restrict__ yy,
                                                  u64* __restrict__ strongP,
                                                  u64* __restrict__ weakP) {
    const int wid = blockIdx.x * 4 + (threadIdx.x >> 6);
    const int lane = threadIdx.x & 63;

    const int n = wid / (NSTRIP * NBAND);
    const int rem = wid - n * (NSTRIP * NBAND);
    const int s = rem / NBAND;
    const int band = rem - s * NBAND;
    const int y0 = band * RB;
    const float* src = (n < 16) ? (yhat + (size_t)n * 3 * IMG)
                                : (yy + (size_t)(n - 16) * 3 * IMG);
    const float* __restrict__ srcR = src;
    const float* __restrict__ srcG = src + IMG;
    const float* __restrict__ srcB = src + 2 * IMG;

    const int c = s * SW - 4 + lane;
    const int cx = reflect_idx(c, W);
    const bool colok = ((unsigned)c < (unsigned)W);
    const u64 omask = (s == 9) ? 0xFFull : 0x00FFFFFFFFFFFFFFull;

    const int aM1 = ((lane - 1) << 2), aP1 = ((lane + 1) << 2);
    const int aM2 = ((lane - 2) << 2), aP2 = ((lane + 2) << 2);
    const int aM3 = ((lane - 3) << 2), aP3 = ((lane + 3) << 2);

    float hx[8], hy[8];
#pragma unroll
    for (int j = 0; j < 8; j++) { hx[j] = 0.f; hy[j] = 0.f; }

    const u64 outBase = ((size_t)n * NSTRIP + s) * H;

    // ping-pong prefetch register sets: A = even pairs, B = odd pairs
    float rA0, gA0, bA0, rA1, gA1, bA1;
    float rB0, gB0, bB0, rB1, gB1, bB1;

    // load gray-source rows y0-4+2kk, y0-3+2kk into set S
#define LOADP(S, kk)                                                            \
    {                                                                           \
        int ya = y0 - 4 + 2 * (kk), yb = ya + 1;                                \
        int ia = reflect_idx(ya, H), ib = reflect_idx(yb, H);                   \
        int voa = (ia << 9) + cx, vob = (ib << 9) + cx;                         \
        r##S##0 = srcR[voa]; g##S##0 = srcG[voa]; b##S##0 = srcB[voa];          \
        r##S##1 = srcR[vob]; g##S##1 = srcG[vob]; b##S##1 = srcB[vob];          \
    }

    // issue 6 bpermutes for one gray row into scoped temps t*
#define SHUF6(gv, t)                                                            \
    float t##m1 = bperm_f(aM1, gv), t##p1 = bperm_f(aP1, gv);                   \
    float t##m2 = bperm_f(aM2, gv), t##p2 = bperm_f(aP2, gv);                   \
    float t##m3 = bperm_f(aM3, gv), t##p3 = bperm_f(aP3, gv);

    // combine shuffles into ring slot P (compile-time literal)
#define COMB(gv, t, P)                                                          \
    hx[(P) & 7] = A3c * (t##p1 - t##m1) + A2c * (t##p2 - t##m2)                 \
                + A1c * (t##p3 - t##m3);                                        \
    hy[(P) & 7] = S3c * (gv) + S2c * (t##p1 + t##m1) + S1c * (t##p2 + t##m2)    \
                + S0c * (t##p3 + t##m3);

    // mag^2 + L/R + dir for ring center CP (literal); row mr gates validity
#define MAG_AT(CP, mr, mv, mvL, mvR, dv)                                        \
    {                                                                           \
        float gx = S3c * hx[(CP) & 7]                                           \
                 + S2c * (hx[((CP) + 1) & 7] + hx[((CP) + 7) & 7])              \
                 + S1c * (hx[((CP) + 2) & 7] + hx[((CP) + 6) & 7])              \
                 + S0c * (hx[((CP) + 3) & 7] + hx[((CP) + 5) & 7]);             \
        float gy = A3c * (hy[((CP) + 1) & 7] - hy[((CP) + 7) & 7])              \
                 + A2c * (hy[((CP) + 2) & 7] - hy[((CP) + 6) & 7])              \
                 + A1c * (hy[((CP) + 3) & 7] - hy[((CP) + 5) & 7]);             \
        bool okm = colok && ((unsigned)(mr) < (unsigned)H);                     \
        mv = okm ? (gx * gx + gy * gy + 1e-12f) : 0.f;                          \
        mvL = bperm_f(aM1, mv);                                                 \
        mvR = bperm_f(aP1, mv);                                                 \
        float ax = fabsf(gx), ay = fabsf(gy);                                   \
        dv = (ay <= 0.4142135623730951f * ax) ? 0                               \
           : (ay >= 2.414213562373095f * ax) ? 2                                \
           : (((gx > 0.f) == (gy > 0.f)) ? 1 : 3);                              \
    }

#define GRAY0(S) (0.299f * r##S##0 + 0.587f * g##S##0 + 0.114f * b##S##0)
#define GRAY1(S) (0.299f * r##S##1 + 0.587f * g##S##1 + 0.114f * b##S##1)

    LOADP(A, 0);
    LOADP(B, 1);

    // ---- prime pairs 0..2: fill ring slots 0..5 (gray rows y0-4..y0+1) ----
#define PRIME(kk, S)                                                            \
    {                                                                           \
        float ga = GRAY0(S);                                                    \
        float gb = GRAY1(S);                                                    \
        LOADP(S, (kk) + 2);                                                     \
        SHUF6(ga, ta)                                                           \
        SHUF6(gb, tb)                                                           \
        COMB(ga, ta, 2 * (kk))                                                  \
        COMB(gb, tb, 2 * (kk) + 1)                                              \
    }
    PRIME(0, A)
    PRIME(1, B)
    PRIME(2, A)
#undef PRIME

    // pair 3 (B): gray rows y0+2,y0+3 -> mag rows y0-1, y0
    float mm1, mm1L, mm1R, m0, m0L, m0R;
    int dir0;
    {
        float ga = GRAY0(B);
        float gb = GRAY1(B);
        LOADP(B, 5);
        SHUF6(ga, ta)
        SHUF6(gb, tb)
        COMB(ga, ta, 6)
        int dtmp;
        MAG_AT(3, y0 - 1, mm1, mm1L, mm1R, dtmp);
        (void)dtmp;
        COMB(gb, tb, 7)
        MAG_AT(4, y0, m0, m0L, m0R, dir0);
    }

    // ---- steady step: jj = k&3 (literal ring phase), S = parity reg set ----
#define STEP(jj, k, S, DOPREF)                                                  \
    {                                                                           \
        float ga = GRAY0(S);                                                    \
        float gb = GRAY1(S);                                                    \
        if (DOPREF) LOADP(S, (k) + 2);                                          \
        SHUF6(ga, ta)                                                           \
        SHUF6(gb, tb)                                                           \
        float ma, maL, maR, mb, mbL, mbR;                                       \
        int da, db;                                                             \
        COMB(ga, ta, 2 * (jj))                                                  \
        MAG_AT((2 * (jj) + 5) & 7, y0 + 2 * (k) - 7, ma, maL, maR, da);         \
        COMB(gb, tb, 2 * (jj) + 1)                                              \
        MAG_AT((2 * (jj) + 6) & 7, y0 + 2 * (k) - 6, mb, mbL, mbR, db);         \
        /* row t0 = y0+2k-8: mags (mm1, m0, ma), dir0 */                        \
        float n1 = (dir0 == 0) ? m0R : (dir0 == 1) ? maR : (dir0 == 2) ? ma : maL; \
        float n2 = (dir0 == 0) ? m0L : (dir0 == 1) ? mm1L : (dir0 == 2) ? mm1 : mm1R; \
        bool ok0 = (m0 >= n1) && (m0 >= n2);                                    \
        u64 bs0 = __ballot(ok0 && (m0 >= 0.04f));                               \
        u64 bw0 = __ballot(ok0 && (m0 >= 0.01f));                               \
        /* row t1 = t0+1: mags (m0, ma, mb), dir = da */                        \
        float n3 = (da == 0) ? maR : (da == 1) ? mbR : (da == 2) ? mb : mbL;    \
        float n4 = (da == 0) ? maL : (da == 1) ? m0L : (da == 2) ? m0 : m0R;    \
        bool ok1 = (ma >= n3) && (ma >= n4);                                    \
        u64 bs1 = __ballot(ok1 && (ma >= 0.04f));                               \
        u64 bw1 = __ballot(ok1 && (ma >= 0.01f));                               \
        if (lane == 0) {                                                        \
            int t0 = y0 + 2 * (k) - 8;                                          \
            ulonglong2 vs, vw;                                                  \
            vs.x = (bs0 >> 4) & omask; vs.y = (bs1 >> 4) & omask;               \
            vw.x = (bw0 >> 4) & omask; vw.y = (bw1 >> 4) & omask;               \
            *(ulonglong2*)&strongP[outBase + t0] = vs;                          \
            *(ulonglong2*)&weakP[outBase + t0] = vw;                            \
        }                                                                       \
        mm1 = ma; mm1L = maL; mm1R = maR;                                       \
        m0 = mb; m0L = mbL; m0R = mbR;                                          \
        dir0 = db;                                                              \
    }

    // steady pairs k=4..19; even->A, odd->B; last prefetch at k=17 (pair 19)
#pragma unroll 1
    for (int k4 = 4; k4 < 16; k4 += 4) {
        STEP(0, k4 + 0, A, true);
        STEP(1, k4 + 1, B, true);
        STEP(2, k4 + 2, A, true);
        STEP(3, k4 + 3, B, true);
    }
    STEP(0, 16, A, true);
    STEP(1, 17, B, true);
    STEP(2, 18, A, false);
    STEP(3, 19, B, false);

#undef STEP
#undef MAG_AT
#undef COMB
#undef SHUF6
#undef LOADP
#undef GRAY0
#undef GRAY1
}

// ---------------------------------------------------------------------------
// Kernel 2: bit-parallel hysteresis (10 iters, exact via light cone) + diff
// count -> per-block partial. NO device fence / atomics: the fused-finalize
// variant's per-block __threadfence() cost ~20-25 us total on gfx950 (L2
// writeback across non-coherent XCDs, x1024 blocks). Kernel-boundary
// ordering + separate k_final is ~2 us.
// One wave per 32x32 tile per image-pair; lane l = row ty0-10+l.
// Loads from 56-bit strip words via 3-word funnel shift (coalesced: lane=y).
// ---------------------------------------------------------------------------
__device__ __forceinline__ u64 ldw10(const u64* p, int img, int y, int q, bool ok) {
    return (ok && q >= 0 && q < NSTRIP) ? p[((size_t)img * NSTRIP + q) * H + y] : 0ULL;
}

__global__ __launch_bounds__(256) void k_hyst(const u64* __restrict__ strongP,
                                              const u64* __restrict__ weakP,
                                              unsigned int* __restrict__ partials) {
    __shared__ unsigned int part[4];
    const int wy = threadIdx.x >> 6;
    const int wave = blockIdx.x * 4 + wy;
    const int lane = threadIdx.x & 63;
    const int tile = wave & 255;
    const int pair = wave >> 8;          // 0..15
    const int tx0 = (tile & 15) * 32;
    const int ty0 = (tile >> 4) * 32;

    const int y = ty0 - 10 + lane;
    const bool rowok = (lane < 52) && (y >= 0) && (y < H);
    const int yc = rowok ? y : 0;

    const int x = tx0 - 10;
    const int q0 = (x < 0) ? -1 : (x / 56);
    const int r = x - 56 * q0;           // 1..55, never 0
    const int sh1 = 56 - r;
    const bool need3 = (r > 48);
    const int sh2 = 112 - r;

    const int imgA = pair, imgB = pair + 16;
    u64 sA, wA, sB, wB;
    {
        u64 w0, w1, w2;
        w0 = ldw10(strongP, imgA, yc, q0, rowok);
        w1 = ldw10(strongP, imgA, yc, q0 + 1, rowok);
        w2 = need3 ? ldw10(strongP, imgA, yc, q0 + 2, rowok) : 0ULL;
        sA = (w0 >> r) | (w1 << sh1) | (need3 ? (w2 << sh2) : 0ULL);
        w0 = ldw10(weakP, imgA, yc, q0, rowok);
        w1 = ldw10(weakP, imgA, yc, q0 + 1, rowok);
        w2 = need3 ? ldw10(weakP, imgA, yc, q0 + 2, rowok) : 0ULL;
        wA = (w0 >> r) | (w1 << sh1) | (need3 ? (w2 << sh2) : 0ULL);
        w0 = ldw10(strongP, imgB, yc, q0, rowok);
        w1 = ldw10(strongP, imgB, yc, q0 + 1, rowok);
        w2 = need3 ? ldw10(strongP, imgB, yc, q0 + 2, rowok) : 0ULL;
        sB = (w0 >> r) | (w1 << sh1) | (need3 ? (w2 << sh2) : 0ULL);
        w0 = ldw10(weakP, imgB, yc, q0, rowok);
        w1 = ldw10(weakP, imgB, yc, q0 + 1, rowok);
        w2 = need3 ? ldw10(weakP, imgB, yc, q0 + 2, rowok) : 0ULL;
        wB = (w0 >> r) | (w1 << sh1) | (need3 ? (w2 << sh2) : 0ULL);
    }

#pragma unroll
    for (int it = 0; it < 10; it++) {
        u64 up = __shfl_up(sA, 1), dn = __shfl_down(sA, 1);
        u64 t = up | sA | dn;
        sA |= (t | (t << 1) | (t >> 1)) & wA;
        up = __shfl_up(sB, 1); dn = __shfl_down(sB, 1);
        t = up | sB | dn;
        sB |= (t | (t << 1) | (t >> 1)) & wB;
    }

    unsigned int cgt = 0;
    if (lane >= 10 && lane < 42) {
        const u64 mask = ((1ULL << 42) - (1ULL << 10));
        cgt = (unsigned int)__popcll((sA ^ sB) & mask);
    }
#pragma unroll
    for (int off = 32; off > 0; off >>= 1) cgt += __shfl_down(cgt, off);
    if (lane == 0) part[wy] = cgt;
    __syncthreads();
    if (threadIdx.x == 0)
        partials[blockIdx.x] = part[0] + part[1] + part[2] + part[3];
}

// ---------------------------------------------------------------------------
// Kernel 3: sum 1024 partials, scale, write scalar. One block.
// ---------------------------------------------------------------------------
__global__ __launch_bounds__(256) void k_final(const unsigned int* __restrict__ partials,
                                               float* __restrict__ out) {
    __shared__ unsigned int part[4];
    unsigned int c = 0;
    for (int i = threadIdx.x; i < 1024; i += 256) c += partials[i];
#pragma unroll
    for (int off = 32; off > 0; off >>= 1) c += __shfl_down(c, off);
    const int lane = threadIdx.x & 63;
    const int wy = threadIdx.x >> 6;
    if (lane == 0) part[wy] = c;
    __syncthreads();
    if (threadIdx.x == 0)
        out[0] = (float)(part[0] + part[1] + part[2] + part[3]) * (1.0f / 4194304.0f);
}

extern "C" void kernel_launch(void* const* d_in, const int* in_sizes, int n_in,
                              void* d_out, int out_size, void* d_ws, size_t ws_size,
                              hipStream_t stream) {
    const float* yhat = (const float*)d_in[0];
    const float* yy = (const float*)d_in[1];

    u64* strongP = (u64*)d_ws;                        // 32*10*512 u64 = 1.31 MB
    u64* weakP = strongP + (size_t)NIMG * NSTRIP * H; // 1.31 MB
    unsigned int* partials = (unsigned int*)(weakP + (size_t)NIMG * NSTRIP * H);

    // 32 img x 10 strips x 16 bands = 5120 waves, 4 waves/block, 5 blk/CU
    k_edges<<<1280, 256, 0, stream>>>(yhat, yy, strongP, weakP);

    // 256 tiles x 16 pairs = 4096 waves, 4 waves/block
    k_hyst<<<1024, 256, 0, stream>>>(strongP, weakP, partials);
    k_final<<<1, 256, 0, stream>>>(partials, (float*)d_out);
}

// Round 7
// 135.601 us; speedup vs baseline: 1.6975x; 1.0040x over previous
//
#include <hip/hip_runtime.h>
#include <math.h>

#define H 512
#define W 512
#define IMG (H*W)
#define NIMG 32           // 16 images from y_hat + 16 from y
#define NSTRIP 10         // 56-col output strips per row
#define SW 56
#define RB 32             // output rows per band (one cohort: 5120 waves, 5 blk/CU)
#define NBAND 16          // 16*32 = 512 exactly

typedef unsigned long long u64;

__device__ __forceinline__ int reflect_idx(int i, int n) {
    if (i < 0) i = -i;
    if (i >= n) i = 2 * n - 2 - i;
    return i;
}

// All cross-lane via ds_bpermute (r0/r4-proven): no VALU->DPP hazard nops; DS
// latency cross-hides across the 5 resident waves/SIMD.
// r5 lesson: do NOT software-pipeline shuffles across pairs (+26 live temps
// -> allocator spills, 3.3x slowdown). This round's deferred-NMS adds only
// +4 carried regs; spill tripwire = WRITE_SIZE >> 4 MB.
__device__ __forceinline__ float bperm_f(int addr, float v) {
    return __int_as_float(__builtin_amdgcn_ds_bpermute(addr, __float_as_int(v)));
}

// Composed 7-tap kernels: blur(5-tap gaussian) composed with sobel [1,2,1]/[-1,0,1].
#define S0c 0.05448868454964294f
#define S1c 0.35317871110251920f
#define S2c 0.94551131545035710f
#define S3c 1.29364257779496160f
#define A1c 0.05448868454964294f
#define A2c 0.24420134200323332f
#define A3c 0.34813126234460456f

// ---------------------------------------------------------------------------
// Kernel 1 (line-scan, row-PAIR, depth-2 load prefetch, DEFERRED NMS):
// one wave per (image,strip,band). Lane = gray col 56s-4+lane.
//  - Ping-pong load sets A/B, loads issued 2 pair-bodies before use.
//  - Ring h-FIFO depth 8, literal indices (zero FIFO movs).
//  - NMS window shifted back one row vs the mag being computed: step k
//    computes mag rows (2k-7, 2k-6) but stores NMS rows (2k-9, 2k-8) from
//    CARRIED mag rows. Consequence: the freshly-shuffled mbL/mbR are first
//    consumed in the NEXT step (~250 cy cover) and maL/maR get ~100 cy —
//    the per-step lgkmcnt stall of the r6 form (mb shuffles at ~30 cy) is
//    gone. Carries: 3 mag rows (m3 above, m2 center, m1 below) + 2 dirs.
// Output: 56-bit words, plane[img][strip][row]; two 8B stores per step
// (rows are odd/even split by the shift, so no 16B pairing).
// ---------------------------------------------------------------------------
__global__ __launch_bounds__(256, 5) void k_edges(const float* __restrict__ yhat,
                                                  const float* __restrict__ yy,
                                                  u64* __restrict__ strongP,
                                                  u64* __restrict__ weakP) {
    const int wid = blockIdx.x * 4 + (threadIdx.x >> 6);
    const int lane = threadIdx.x & 63;

    const int n = wid / (NSTRIP * NBAND);
    const int rem = wid - n * (NSTRIP * NBAND);
    const int s = rem / NBAND;
    const int band = rem - s * NBAND;
    const int y0 = band * RB;
    const float* src = (n < 16) ? (yhat + (size_t)n * 3 * IMG)
                                : (yy + (size_t)(n - 16) * 3 * IMG);
    const float* __restrict__ srcR = src;
    const float* __restrict__ srcG = src + IMG;
    const float* __restrict__ srcB = src + 2 * IMG;

    const int c = s * SW - 4 + lane;
    const int cx = reflect_idx(c, W);
    const bool colok = ((unsigned)c < (unsigned)W);
    const u64 omask = (s == 9) ? 0xFFull : 0x00FFFFFFFFFFFFFFull;

    const int aM1 = ((lane - 1) << 2), aP1 = ((lane + 1) << 2);
    const int aM2 = ((lane - 2) << 2), aP2 = ((lane + 2) << 2);
    const int aM3 = ((lane - 3) << 2), aP3 = ((lane + 3) << 2);

    float hx[8], hy[8];
#pragma unroll
    for (int j = 0; j < 8; j++) { hx[j] = 0.f; hy[j] = 0.f; }

    const u64 outBase = ((size_t)n * NSTRIP + s) * H;

    // ping-pong prefetch register sets: A = even pairs, B = odd pairs
    float rA0, gA0, bA0, rA1, gA1, bA1;
    float rB0, gB0, bB0, rB1, gB1, bB1;

    // load gray-source rows y0-4+2kk, y0-3+2kk into set S
#define LOADP(S, kk)                                                            \
    {                                                                           \
        int ya = y0 - 4 + 2 * (kk), yb = ya + 1;                                \
        int ia = reflect_idx(ya, H), ib = reflect_idx(yb, H);                   \
        int voa = (ia << 9) + cx, vob = (ib << 9) + cx;                         \
        r##S##0 = srcR[voa]; g##S##0 = srcG[voa]; b##S##0 = srcB[voa];          \
        r##S##1 = srcR[vob]; g##S##1 = srcG[vob]; b##S##1 = srcB[vob];          \
    }

    // issue 6 bpermutes for one gray row into scoped temps t*
#define SHUF6(gv, t)                                                            \
    float t##m1 = bperm_f(aM1, gv), t##p1 = bperm_f(aP1, gv);                   \
    float t##m2 = bperm_f(aM2, gv), t##p2 = bperm_f(aP2, gv);                   \
    float t##m3 = bperm_f(aM3, gv), t##p3 = bperm_f(aP3, gv);

    // combine shuffles into ring slot P (compile-time literal)
#define COMB(gv, t, P)                                                          \
    hx[(P) & 7] = A3c * (t##p1 - t##m1) + A2c * (t##p2 - t##m2)                 \
                + A1c * (t##p3 - t##m3);                                        \
    hy[(P) & 7] = S3c * (gv) + S2c * (t##p1 + t##m1) + S1c * (t##p2 + t##m2)    \
                + S0c * (t##p3 + t##m3);

    // mag^2 + L/R + dir for ring center CP (literal); row mr gates validity
#define MAG_AT(CP, mr, mv, mvL, mvR, dv)                                        \
    {                                                                           \
        float gx = S3c * hx[(CP) & 7]                                           \
                 + S2c * (hx[((CP) + 1) & 7] + hx[((CP) + 7) & 7])              \
                 + S1c * (hx[((CP) + 2) & 7] + hx[((CP) + 6) & 7])              \
                 + S0c * (hx[((CP) + 3) & 7] + hx[((CP) + 5) & 7]);             \
        float gy = A3c * (hy[((CP) + 1) & 7] - hy[((CP) + 7) & 7])              \
                 + A2c * (hy[((CP) + 2) & 7] - hy[((CP) + 6) & 7])              \
                 + A1c * (hy[((CP) + 3) & 7] - hy[((CP) + 5) & 7]);             \
        bool okm = colok && ((unsigned)(mr) < (unsigned)H);                     \
        mv = okm ? (gx * gx + gy * gy + 1e-12f) : 0.f;                          \
        mvL = bperm_f(aM1, mv);                                                 \
        mvR = bperm_f(aP1, mv);                                                 \
        float ax = fabsf(gx), ay = fabsf(gy);                                   \
        dv = (ay <= 0.4142135623730951f * ax) ? 0                               \
           : (ay >= 2.414213562373095f * ax) ? 2                                \
           : (((gx > 0.f) == (gy > 0.f)) ? 1 : 3);                              \
    }

#define GRAY0(S) (0.299f * r##S##0 + 0.587f * g##S##0 + 0.114f * b##S##0)
#define GRAY1(S) (0.299f * r##S##1 + 0.587f * g##S##1 + 0.114f * b##S##1)

    LOADP(A, 0);
    LOADP(B, 1);

    // ---- prime pairs 0..2: fill ring slots 0..5 (gray rows y0-4..y0+1) ----
#define PRIME(kk, S)                                                            \
    {                                                                           \
        float ga = GRAY0(S);                                                    \
        float gb = GRAY1(S);                                                    \
        LOADP(S, (kk) + 2);                                                     \
        SHUF6(ga, ta)                                                           \
        SHUF6(gb, tb)                                                           \
        COMB(ga, ta, 2 * (kk))                                                  \
        COMB(gb, tb, 2 * (kk) + 1)                                              \
    }
    PRIME(0, A)
    PRIME(1, B)
    PRIME(2, A)
#undef PRIME

    // Carried NMS state entering step k:
    //   m3* = mag row y0+2k-10 (above)   [no dir needed]
    //   m2* = mag row y0+2k-9  (t0 center), dir2
    //   m1* = mag row y0+2k-8  (t1 center), dir1
    float m1, m1L, m1R, m2, m2L, m2R, m3, m3L, m3R;
    int dir1, dir2;

    // pair 3 (B): gray rows y0+2,y0+3 -> mag rows y0-1 (m2), y0 (m1).
    // m3 (row y0-2) only feeds the suppressed first t0 -> init 0.
    {
        float ga = GRAY0(B);
        SHUF6(ga, ta)
        float gb = GRAY1(B);
        LOADP(B, 5);
        SHUF6(gb, tb)
        COMB(ga, ta, 6)
        int dtmp;
        MAG_AT(3, y0 - 1, m2, m2L, m2R, dtmp);
        (void)dtmp;
        dir2 = 0;
        COMB(gb, tb, 7)
        MAG_AT(4, y0, m1, m1L, m1R, dir1);
        m3 = 0.f; m3L = 0.f; m3R = 0.f;
    }

    // ---- steady step: jj = k&3 (literal ring phase), S = parity reg set.
    // Computes mag rows (2k-7 = ma, 2k-6 = mb); stores NMS rows
    // t0 = y0+2k-9 (center m2, above m3, below m1)  [W0 gates: k=4 row
    // belongs to the previous band] and t1 = y0+2k-8 (center m1, above m2,
    // below ma). mb's shuffles are consumed next step. ----
#define STEP(jj, k, S, DOPREF, W0)                                              \
    {                                                                           \
        float ga = GRAY0(S);                                                    \
        SHUF6(ga, ta)                                                           \
        float gb = GRAY1(S);                                                    \
        if (DOPREF) LOADP(S, (k) + 2);                                          \
        SHUF6(gb, tb)                                                           \
        float ma, maL, maR, mb, mbL, mbR;                                       \
        int da, db;                                                             \
        COMB(ga, ta, 2 * (jj))                                                  \
        MAG_AT((2 * (jj) + 5) & 7, y0 + 2 * (k) - 7, ma, maL, maR, da);         \
        if (W0) {                                                               \
            float n1 = (dir2 == 0) ? m2R : (dir2 == 1) ? m1R : (dir2 == 2) ? m1 : m1L; \
            float n2 = (dir2 == 0) ? m2L : (dir2 == 1) ? m3L : (dir2 == 2) ? m3 : m3R; \
            bool ok0 = (m2 >= n1) && (m2 >= n2);                                \
            u64 bs0 = __ballot(ok0 && (m2 >= 0.04f));                           \
            u64 bw0 = __ballot(ok0 && (m2 >= 0.01f));                           \
            if (lane == 0) {                                                    \
                strongP[outBase + y0 + 2 * (k) - 9] = (bs0 >> 4) & omask;       \
                weakP[outBase + y0 + 2 * (k) - 9] = (bw0 >> 4) & omask;         \
            }                                                                   \
        }                                                                       \
        COMB(gb, tb, 2 * (jj) + 1)                                              \
        MAG_AT((2 * (jj) + 6) & 7, y0 + 2 * (k) - 6, mb, mbL, mbR, db);         \
        {                                                                       \
            float n3 = (dir1 == 0) ? m1R : (dir1 == 1) ? maR : (dir1 == 2) ? ma : maL; \
            float n4 = (dir1 == 0) ? m1L : (dir1 == 1) ? m2L : (dir1 == 2) ? m2 : m2R; \
            bool ok1 = (m1 >= n3) && (m1 >= n4);                                \
            u64 bs1 = __ballot(ok1 && (m1 >= 0.04f));                           \
            u64 bw1 = __ballot(ok1 && (m1 >= 0.01f));                           \
            if (lane == 0) {                                                    \
                strongP[outBase + y0 + 2 * (k) - 8] = (bs1 >> 4) & omask;       \
                weakP[outBase + y0 + 2 * (k) - 8] = (bw1 >> 4) & omask;         \
            }                                                                   \
        }                                                                       \
        m3 = m1; m3L = m1L; m3R = m1R;                                          \
        m2 = ma; m2L = maL; m2R = maR; dir2 = da;                               \
        m1 = mb; m1L = mbL; m1R = mbR; dir1 = db;                               \
    }

    // steady pairs k=4..19; even->A, odd->B. k=4 suppresses t0 (row y0-1:
    // previous band's row 31, identical value but stored there). Last loads
    // at k=17 (pair 19).
    STEP(0, 4, A, true, false)
#pragma unroll 1
    for (int k4 = 5; k4 <= 13; k4 += 4) {
        STEP(1, k4 + 0, B, true, true)
        STEP(2, k4 + 1, A, true, true)
        STEP(3, k4 + 2, B, true, true)
        STEP(0, k4 + 3, A, true, true)
    }
    STEP(1, 17, B, true, true)
    STEP(2, 18, A, false, true)
    STEP(3, 19, B, false, true)

    // epilogue: row y0+31 (center m2/dir2, above m3, below m1 = row y0+32,
    // zero-gated at the image edge exactly like the reference zero-pad).
    {
        float n1 = (dir2 == 0) ? m2R : (dir2 == 1) ? m1R : (dir2 == 2) ? m1 : m1L;
        float n2 = (dir2 == 0) ? m2L : (dir2 == 1) ? m3L : (dir2 == 2) ? m3 : m3R;
        bool ok = (m2 >= n1) && (m2 >= n2);
        u64 bs = __ballot(ok && (m2 >= 0.04f));
        u64 bw = __ballot(ok && (m2 >= 0.01f));
        if (lane == 0) {
            strongP[outBase + y0 + 31] = (bs >> 4) & omask;
            weakP[outBase + y0 + 31] = (bw >> 4) & omask;
        }
    }

#undef STEP
#undef MAG_AT
#undef COMB
#undef SHUF6
#undef LOADP
#undef GRAY0
#undef GRAY1
}

// ---------------------------------------------------------------------------
// Kernel 2: bit-parallel hysteresis (10 iters, exact via light cone) + diff
// count -> per-block partial. NO device fence / atomics: the fused-finalize
// variant's per-block __threadfence() cost ~20-25 us total on gfx950 (L2
// writeback across non-coherent XCDs, x1024 blocks). Kernel-boundary
// ordering + separate k_final is ~2 us.
// One wave per 32x32 tile per image-pair; lane l = row ty0-10+l.
// Loads from 56-bit strip words via 3-word funnel shift (coalesced: lane=y).
// ---------------------------------------------------------------------------
__device__ __forceinline__ u64 ldw10(const u64* p, int img, int y, int q, bool ok) {
    return (ok && q >= 0 && q < NSTRIP) ? p[((size_t)img * NSTRIP + q) * H + y] : 0ULL;
}

__global__ __launch_bounds__(256) void k_hyst(const u64* __restrict__ strongP,
                                              const u64* __restrict__ weakP,
                                              unsigned int* __restrict__ partials) {
    __shared__ unsigned int part[4];
    const int wy = threadIdx.x >> 6;
    const int wave = blockIdx.x * 4 + wy;
    const int lane = threadIdx.x & 63;
    const int tile = wave & 255;
    const int pair = wave >> 8;          // 0..15
    const int tx0 = (tile & 15) * 32;
    const int ty0 = (tile >> 4) * 32;

    const int y = ty0 - 10 + lane;
    const bool rowok = (lane < 52) && (y >= 0) && (y < H);
    const int yc = rowok ? y : 0;

    const int x = tx0 - 10;
    const int q0 = (x < 0) ? -1 : (x / 56);
    const int r = x - 56 * q0;           // 1..55, never 0
    const int sh1 = 56 - r;
    const bool need3 = (r > 48);
    const int sh2 = 112 - r;

    const int imgA = pair, imgB = pair + 16;
    u64 sA, wA, sB, wB;
    {
        u64 w0, w1, w2;
        w0 = ldw10(strongP, imgA, yc, q0, rowok);
        w1 = ldw10(strongP, imgA, yc, q0 + 1, rowok);
        w2 = need3 ? ldw10(strongP, imgA, yc, q0 + 2, rowok) : 0ULL;
        sA = (w0 >> r) | (w1 << sh1) | (need3 ? (w2 << sh2) : 0ULL);
        w0 = ldw10(weakP, imgA, yc, q0, rowok);
        w1 = ldw10(weakP, imgA, yc, q0 + 1, rowok);
        w2 = need3 ? ldw10(weakP, imgA, yc, q0 + 2, rowok) : 0ULL;
        wA = (w0 >> r) | (w1 << sh1) | (need3 ? (w2 << sh2) : 0ULL);
        w0 = ldw10(strongP, imgB, yc, q0, rowok);
        w1 = ldw10(strongP, imgB, yc, q0 + 1, rowok);
        w2 = need3 ? ldw10(strongP, imgB, yc, q0 + 2, rowok) : 0ULL;
        sB = (w0 >> r) | (w1 << sh1) | (need3 ? (w2 << sh2) : 0ULL);
        w0 = ldw10(weakP, imgB, yc, q0, rowok);
        w1 = ldw10(weakP, imgB, yc, q0 + 1, rowok);
        w2 = need3 ? ldw10(weakP, imgB, yc, q0 + 2, rowok) : 0ULL;
        wB = (w0 >> r) | (w1 << sh1) | (need3 ? (w2 << sh2) : 0ULL);
    }

#pragma unroll
    for (int it = 0; it < 10; it++) {
        u64 up = __shfl_up(sA, 1), dn = __shfl_down(sA, 1);
        u64 t = up | sA | dn;
        sA |= (t | (t << 1) | (t >> 1)) & wA;
        up = __shfl_up(sB, 1); dn = __shfl_down(sB, 1);
        t = up | sB | dn;
        sB |= (t | (t << 1) | (t >> 1)) & wB;
    }

    unsigned int cgt = 0;
    if (lane >= 10 && lane < 42) {
        const u64 mask = ((1ULL << 42) - (1ULL << 10));
        cgt = (unsigned int)__popcll((sA ^ sB) & mask);
    }
#pragma unroll
    for (int off = 32; off > 0; off >>= 1) cgt += __shfl_down(cgt, off);
    if (lane == 0) part[wy] = cgt;
    __syncthreads();
    if (threadIdx.x == 0)
        partials[blockIdx.x] = part[0] + part[1] + part[2] + part[3];
}

// ---------------------------------------------------------------------------
// Kernel 3: sum 1024 partials, scale, write scalar. One block.
// ---------------------------------------------------------------------------
__global__ __launch_bounds__(256) void k_final(const unsigned int* __restrict__ partials,
                                               float* __restrict__ out) {
    __shared__ unsigned int part[4];
    unsigned int c = 0;
    for (int i = threadIdx.x; i < 1024; i += 256) c += partials[i];
#pragma unroll
    for (int off = 32; off > 0; off >>= 1) c += __shfl_down(c, off);
    const int lane = threadIdx.x & 63;
    const int wy = threadIdx.x >> 6;
    if (lane == 0) part[wy] = c;
    __syncthreads();
    if (threadIdx.x == 0)
        out[0] = (float)(part[0] + part[1] + part[2] + part[3]) * (1.0f / 4194304.0f);
}

extern "C" void kernel_launch(void* const* d_in, const int* in_sizes, int n_in,
                              void* d_out, int out_size, void* d_ws, size_t ws_size,
                              hipStream_t stream) {
    const float* yhat = (const float*)d_in[0];
    const float* yy = (const float*)d_in[1];

    u64* strongP = (u64*)d_ws;                        // 32*10*512 u64 = 1.31 MB
    u64* weakP = strongP + (size_t)NIMG * NSTRIP * H; // 1.31 MB
    unsigned int* partials = (unsigned int*)(weakP + (size_t)NIMG * NSTRIP * H);

    // 32 img x 10 strips x 16 bands = 5120 waves, 4 waves/block, 5 blk/CU
    k_edges<<<1280, 256, 0, stream>>>(yhat, yy, strongP, weakP);

    // 256 tiles x 16 pairs = 4096 waves, 4 waves/block
    k_hyst<<<1024, 256, 0, stream>>>(strongP, weakP, partials);
    k_final<<<1, 256, 0, stream>>>(partials, (float*)d_out);
}